// Round 1
// baseline (605.975 us; speedup 1.0000x reference)
//
#include <hip/hip_runtime.h>

#define Bb 16
#define Ll 2048
#define Hh 768
#define Dd 64
#define Cc 64
#define HC 48
#define NT (Hh / HC)   // 16 h-tiles
#define NCH (Ll / Cc)  // 32 chunks

// physical column for logical (row r, col d) in XOR-swizzled [64][64] LDS tile
__device__ __forceinline__ int swz_col(int d, int r) {
  return ((((d >> 2) ^ ((r >> 2) & 15)) << 2) | (d & 3));
}

__device__ __forceinline__ void fma4(float4& a, float s, const float4& v) {
  a.x = fmaf(s, v.x, a.x);
  a.y = fmaf(s, v.y, a.y);
  a.z = fmaf(s, v.z, a.z);
  a.w = fmaf(s, v.w, a.w);
}

// Kernel 1: E[t,d] = ae[x[t],d];  F[t,e] = sum_d E[t,d] * w[d,e]
__global__ void ef_kernel(const int* __restrict__ x, const float* __restrict__ ae,
                          const float* __restrict__ w, float* __restrict__ E,
                          float* __restrict__ F) {
  const int wave = threadIdx.x >> 6;
  const int lane = threadIdx.x & 63;
  const int tkn = blockIdx.x * 4 + wave;  // token in [0, B*L)
  __shared__ float sE[4][64];
  const int idx = x[tkn];
  const float e = ae[(size_t)idx * Dd + lane];
  sE[wave][lane] = e;
  E[(size_t)tkn * Dd + lane] = e;
  __syncthreads();
  float f = 0.f;
#pragma unroll
  for (int d = 0; d < Dd; ++d) f = fmaf(sE[wave][d], w[d * Dd + lane], f);
  F[(size_t)tkn * Dd + lane] = f;
}

// Kernel 2: chunked causal scan. grid = (NT h-tiles, B batches), block = 256.
__global__ __launch_bounds__(256) void scan_kernel(const float* __restrict__ bx,
                                                   const float* __restrict__ Eg,
                                                   const float* __restrict__ Fg,
                                                   float* __restrict__ out) {
  const int t = blockIdx.x;   // h tile
  const int b = blockIdx.y;   // batch
  const int tid = threadIdx.x;

  __shared__ float sE[Cc][Dd];      // swizzled  16 KB
  __shared__ float sF[Cc][Dd];      // swizzled  16 KB
  __shared__ float sS[Dd][HC];      // state     12 KB
  __shared__ float sG[Cc][HC];      // (pos+1)*x 12 KB
  __shared__ float sc[Cc][Cc + 1];  // scores    ~16.25 KB

  for (int e = tid; e < Dd * HC; e += 256) (&sS[0][0])[e] = 0.f;
  __syncthreads();

  for (int ch = 0; ch < NCH; ++ch) {
    const int p0 = ch * Cc;

    // ---- A: stage chunk (global -> LDS) ----
    {
      const float4* E4 = (const float4*)(Eg + (size_t)(b * Ll + p0) * Dd);
      const float4* F4 = (const float4*)(Fg + (size_t)(b * Ll + p0) * Dd);
#pragma unroll
      for (int e = 0; e < 4; ++e) {
        const int fi = e * 256 + tid;          // 0..1023
        const int i = fi >> 4;
        const int d4 = fi & 15;
        const int c4 = (d4 ^ ((i >> 2) & 15)) << 2;
        float4 v = E4[fi];
        *(float4*)&sE[i][c4] = v;
        float4 vf = F4[fi];
        *(float4*)&sF[i][c4] = vf;
      }
      const float* Xg = bx + (size_t)(b * Ll + p0) * Hh + t * HC;
#pragma unroll
      for (int e = 0; e < 3; ++e) {
        const int fi = e * 256 + tid;          // 0..767
        const int j = fi / 12;
        const int h4 = fi % 12;
        float4 v = *(const float4*)(Xg + (size_t)j * Hh + (h4 << 2));
        const float s = (float)(p0 + j + 1);
        float4 g;
        g.x = v.x * s; g.y = v.y * s; g.z = v.z * s; g.w = v.w * s;
        *(float4*)&sG[j][h4 << 2] = g;
      }
    }
    __syncthreads();

    // ---- B: intra-chunk scores sc[i][j] = F_i . E_j (only i-block <= j-block needed) ----
    {
      const int tj = tid & 15;
      const int ti = tid >> 4;
      if (ti <= tj) {
        float acc[4][4] = {};
#pragma unroll
        for (int d4 = 0; d4 < 16; ++d4) {
          float4 e4[4], f4[4];
#pragma unroll
          for (int q = 0; q < 4; ++q) {
            e4[q] = *(const float4*)&sE[tj * 4 + q][(d4 ^ tj) << 2];
            f4[q] = *(const float4*)&sF[ti * 4 + q][(d4 ^ ti) << 2];
          }
#pragma unroll
          for (int a = 0; a < 4; ++a)
#pragma unroll
            for (int q = 0; q < 4; ++q)
              acc[a][q] += f4[a].x * e4[q].x + f4[a].y * e4[q].y +
                           f4[a].z * e4[q].z + f4[a].w * e4[q].w;
        }
#pragma unroll
        for (int a = 0; a < 4; ++a)
#pragma unroll
          for (int q = 0; q < 4; ++q) sc[ti * 4 + a][tj * 4 + q] = acc[a][q];
      }
    }
    __syncthreads();

    // ---- C: output: out[j] = inv*(G[j] + E[j].S + sum_{i<j} sc[i][j]*G[i]) ----
    if (tid < 128) {
      const int h4g = tid & 3;   // 3 float4 columns: hb..hb+11
      const int jp = tid >> 2;   // j pair
      const int j0 = jp * 2, j1 = j0 + 1;
      const int hb = h4g * 12;
      float4 a0[3] = {}, a1[3] = {};
      for (int d = 0; d < Dd; ++d) {
        const float e0 = sE[j0][swz_col(d, j0)];
        const float e1 = sE[j1][swz_col(d, j1)];
#pragma unroll
        for (int k = 0; k < 3; ++k) {
          const float4 sv = *(const float4*)&sS[d][hb + (k << 2)];
          fma4(a0[k], e0, sv);
          fma4(a1[k], e1, sv);
        }
      }
      for (int i = 0; i < j0; ++i) {
        const float s0 = sc[i][j0];
        const float s1 = sc[i][j1];
#pragma unroll
        for (int k = 0; k < 3; ++k) {
          const float4 gv = *(const float4*)&sG[i][hb + (k << 2)];
          fma4(a0[k], s0, gv);
          fma4(a1[k], s1, gv);
        }
      }
      {  // i = j0 contributes only to j1
        const float s1 = sc[j0][j1];
#pragma unroll
        for (int k = 0; k < 3; ++k) {
          const float4 gv = *(const float4*)&sG[j0][hb + (k << 2)];
          fma4(a1[k], s1, gv);
        }
      }
      const float inv0 = 1.f / (float)(p0 + j0 + 1);
      const float inv1 = 1.f / (float)(p0 + j1 + 1);
      float* O0 = out + (size_t)(b * Ll + p0 + j0) * Hh + t * HC + hb;
      float* O1 = out + (size_t)(b * Ll + p0 + j1) * Hh + t * HC + hb;
#pragma unroll
      for (int k = 0; k < 3; ++k) {
        const float4 g0 = *(const float4*)&sG[j0][hb + (k << 2)];
        const float4 g1 = *(const float4*)&sG[j1][hb + (k << 2)];
        float4 r0, r1;
        r0.x = inv0 * (g0.x + a0[k].x); r0.y = inv0 * (g0.y + a0[k].y);
        r0.z = inv0 * (g0.z + a0[k].z); r0.w = inv0 * (g0.w + a0[k].w);
        r1.x = inv1 * (g1.x + a1[k].x); r1.y = inv1 * (g1.y + a1[k].y);
        r1.z = inv1 * (g1.z + a1[k].z); r1.w = inv1 * (g1.w + a1[k].w);
        *(float4*)(O0 + (k << 2)) = r0;
        *(float4*)(O1 + (k << 2)) = r1;
      }
    }
    __syncthreads();

    // ---- D: state update S[d][h] += sum_i F[i][d] * G[i][h] ----
    if (tid < 128) {
      const int h4g = tid & 3;
      const int dp = tid >> 2;
      const int d0 = dp * 2, d1 = d0 + 1;
      const int hb = h4g * 12;
      float4 a0[3] = {}, a1[3] = {};
      for (int i = 0; i < Cc; ++i) {
        const float f0 = sF[i][swz_col(d0, i)];
        const float f1 = sF[i][swz_col(d1, i)];
#pragma unroll
        for (int k = 0; k < 3; ++k) {
          const float4 gv = *(const float4*)&sG[i][hb + (k << 2)];
          fma4(a0[k], f0, gv);
          fma4(a1[k], f1, gv);
        }
      }
#pragma unroll
      for (int k = 0; k < 3; ++k) {
        float4* p0v = (float4*)&sS[d0][hb + (k << 2)];
        float4 v0 = *p0v;
        v0.x += a0[k].x; v0.y += a0[k].y; v0.z += a0[k].z; v0.w += a0[k].w;
        *p0v = v0;
        float4* p1v = (float4*)&sS[d1][hb + (k << 2)];
        float4 v1 = *p1v;
        v1.x += a1[k].x; v1.y += a1[k].y; v1.z += a1[k].z; v1.w += a1[k].w;
        *p1v = v1;
      }
    }
    __syncthreads();
  }
}

extern "C" void kernel_launch(void* const* d_in, const int* in_sizes, int n_in,
                              void* d_out, int out_size, void* d_ws, size_t ws_size,
                              hipStream_t stream) {
  (void)in_sizes; (void)n_in; (void)out_size; (void)ws_size;
  const float* bx = (const float*)d_in[0];
  const int* x = (const int*)d_in[1];
  const float* ae = (const float*)d_in[2];
  const float* w = (const float*)d_in[3];
  float* out = (float*)d_out;
  float* E = (float*)d_ws;                         // B*L*D fp32 = 8 MB
  float* F = E + (size_t)Bb * Ll * Dd;             // + 8 MB

  ef_kernel<<<Bb * Ll / 4, 256, 0, stream>>>(x, ae, w, E, F);
  dim3 grid(NT, Bb);
  scan_kernel<<<grid, 256, 0, stream>>>(bx, E, F, out);
}

// Round 2
// 313.932 us; speedup vs baseline: 1.9303x; 1.9303x over previous
//
#include <hip/hip_runtime.h>

#define Bb 16
#define Ll 2048
#define Hh 768
#define Dd 64
#define Cc 64
#define HC 48
#define NT (Hh / HC)   // 16 h-tiles
#define NCH (Ll / Cc)  // 32 chunks

typedef __attribute__((ext_vector_type(8))) short bf16x8;
typedef __attribute__((ext_vector_type(4))) float f32x4;

__device__ __forceinline__ short f2bf(float f) {
  union { float f; unsigned u; } c;
  c.f = f;
  unsigned r = (c.u + 0x7FFFu + ((c.u >> 16) & 1u)) >> 16;
  return (short)r;
}
__device__ __forceinline__ unsigned pack2(float a, float b) {
  return (unsigned)(unsigned short)f2bf(a) | ((unsigned)(unsigned short)f2bf(b) << 16);
}

// ---------------- Prep: per (b,chunk) produce bf16 E[64][64], FT[64][64], scT[64][64] ----------------
__global__ __launch_bounds__(256) void prep_kernel(const int* __restrict__ x,
                                                   const float* __restrict__ ae,
                                                   const float* __restrict__ w,
                                                   short* __restrict__ Eg,
                                                   short* __restrict__ FTg,
                                                   short* __restrict__ scTg) {
  const int b = blockIdx.x >> 5;
  const int ch = blockIdx.x & 31;
  const int tid = threadIdx.x;
  __shared__ float sE[64 * 68];
  __shared__ float sW[64 * 68];
  __shared__ float sF[64 * 68];
  const size_t gb = (size_t)blockIdx.x * 4096;

  // gather E rows (fp32), write bf16 E, stage w
  {
    const int i = tid >> 2, seg = tid & 3;
    const int idx = x[b * Ll + ch * Cc + i];
    const float4* aer = (const float4*)(ae + (size_t)idx * Dd);
    float4 ev[4];
#pragma unroll
    for (int q = 0; q < 4; ++q) {
      ev[q] = aer[seg * 4 + q];
      *(float4*)&sE[i * 68 + seg * 16 + q * 4] = ev[q];
    }
    uint4 p0v, p1v;
    p0v.x = pack2(ev[0].x, ev[0].y); p0v.y = pack2(ev[0].z, ev[0].w);
    p0v.z = pack2(ev[1].x, ev[1].y); p0v.w = pack2(ev[1].z, ev[1].w);
    p1v.x = pack2(ev[2].x, ev[2].y); p1v.y = pack2(ev[2].z, ev[2].w);
    p1v.z = pack2(ev[3].x, ev[3].y); p1v.w = pack2(ev[3].z, ev[3].w);
    *(uint4*)(Eg + gb + i * 64 + seg * 16) = p0v;
    *(uint4*)(Eg + gb + i * 64 + seg * 16 + 8) = p1v;
    const float4* wr = (const float4*)w;
#pragma unroll
    for (int q = 0; q < 4; ++q) {
      const int fl = q * 256 + tid;  // 1024 float4s of w
      const int r = fl >> 4, cc = fl & 15;
      *(float4*)&sW[r * 68 + cc * 4] = wr[fl];
    }
  }
  __syncthreads();

  // F = E * w : thread computes F[i0..i0+3][e0..e0+3]
  {
    const int i0 = (tid >> 4) * 4, e0 = (tid & 15) * 4;
    float accF[4][4] = {};
    for (int d = 0; d < 64; ++d) {
      float e4[4];
#pragma unroll
      for (int a = 0; a < 4; ++a) e4[a] = sE[(i0 + a) * 68 + d];
      const float4 wv = *(const float4*)&sW[d * 68 + e0];
#pragma unroll
      for (int a = 0; a < 4; ++a) {
        accF[a][0] = fmaf(e4[a], wv.x, accF[a][0]);
        accF[a][1] = fmaf(e4[a], wv.y, accF[a][1]);
        accF[a][2] = fmaf(e4[a], wv.z, accF[a][2]);
        accF[a][3] = fmaf(e4[a], wv.w, accF[a][3]);
      }
    }
#pragma unroll
    for (int a = 0; a < 4; ++a) *(float4*)&sF[(i0 + a) * 68 + e0] = *(float4*)accF[a];
  }
  __syncthreads();

  // write FT (bf16, [d][i]) from LDS
  {
    const int d = tid >> 2, iseg = tid & 3;
    float t[16];
#pragma unroll
    for (int q = 0; q < 16; ++q) t[q] = sF[(iseg * 16 + q) * 68 + d];
    uint4 a0, a1;
    a0.x = pack2(t[0], t[1]);  a0.y = pack2(t[2], t[3]);
    a0.z = pack2(t[4], t[5]);  a0.w = pack2(t[6], t[7]);
    a1.x = pack2(t[8], t[9]);  a1.y = pack2(t[10], t[11]);
    a1.z = pack2(t[12], t[13]); a1.w = pack2(t[14], t[15]);
    *(uint4*)(FTg + gb + d * 64 + iseg * 16) = a0;
    *(uint4*)(FTg + gb + d * 64 + iseg * 16 + 8) = a1;
  }

  // sc[i][j] = F_i . E_j ; write scT[j][i] bf16 with strict mask i<j
  {
    const int j0 = (tid >> 4) * 4, i0 = (tid & 15) * 4;
    float acc[4][4] = {};
    for (int d4 = 0; d4 < 16; ++d4) {
      float4 fv[4], ev[4];
#pragma unroll
      for (int q = 0; q < 4; ++q) {
        fv[q] = *(const float4*)&sF[(i0 + q) * 68 + d4 * 4];
        ev[q] = *(const float4*)&sE[(j0 + q) * 68 + d4 * 4];
      }
#pragma unroll
      for (int a = 0; a < 4; ++a)
#pragma unroll
        for (int q = 0; q < 4; ++q)
          acc[a][q] += ev[a].x * fv[q].x + ev[a].y * fv[q].y +
                       ev[a].z * fv[q].z + ev[a].w * fv[q].w;
    }
#pragma unroll
    for (int a = 0; a < 4; ++a) {
      const int j = j0 + a;
      float m[4];
#pragma unroll
      for (int q = 0; q < 4; ++q) m[q] = (i0 + q < j) ? acc[a][q] : 0.f;
      uint2 pv;
      pv.x = pack2(m[0], m[1]);
      pv.y = pack2(m[2], m[3]);
      *(uint2*)(scTg + gb + j * 64 + i0) = pv;
    }
  }
}

// ---------------- Scan: MFMA chunked causal scan ----------------
__global__ __launch_bounds__(256) void scan_kernel(const float* __restrict__ bx,
                                                   const short* __restrict__ Eg,
                                                   const short* __restrict__ FTg,
                                                   const short* __restrict__ scTg,
                                                   float* __restrict__ out) {
  const int tile = blockIdx.x;  // h tile (48 cols)
  const int b = blockIdx.y;
  const int tid = threadIdx.x;
  const int w = tid >> 6;
  const int lane = tid & 63;
  const int quad = lane >> 4;
  const int lq = lane & 15;

  __shared__ short sE[64 * 64];    // A for C2 (rows j, cols d)
  __shared__ short sSc[64 * 64];   // A for C1 (rows j, cols i), strict-masked
  __shared__ short sFT[64 * 64];   // B for D  (rows d, cols i)
  __shared__ short sGT[48 * 64];   // B for C1 / A for D (rows h, cols i)
  __shared__ short sST[48 * 64];   // B for C2 (rows h, cols d) = state^T, bf16

  // zero state
  for (int k2 = tid; k2 < 48 * 64 / 2; k2 += 256) ((int*)sST)[k2] = 0;
  f32x4 accS[3] = {};  // persistent state tiles: (ht, d-tile = w)
  __syncthreads();

  for (int ch = 0; ch < NCH; ++ch) {
    const int p0 = ch * Cc;
    const size_t tb = (size_t)(b * NCH + ch) * 4096;

    // ---- stage bf16 tiles with 16B-block XOR swizzle ----
    {
      const uint4* gE = (const uint4*)(Eg + tb);
      const uint4* gS = (const uint4*)(scTg + tb);
      const uint4* gF = (const uint4*)(FTg + tb);
#pragma unroll
      for (int t2 = 0; t2 < 2; ++t2) {
        const int idx = t2 * 256 + tid;
        const int r = idx >> 3, bl = idx & 7;
        const int dst = r * 64 + ((bl ^ (r & 7)) << 3);
        *(uint4*)&sE[dst] = gE[idx];
        *(uint4*)&sSc[dst] = gS[idx];
        *(uint4*)&sFT[dst] = gF[idx];
      }
      // GT[h][i] = (p0+i+1) * x[b, p0+i, tile*48+h]
      const int i = tid >> 2, hs = tid & 3;
      const float* xr = bx + ((size_t)(b * Ll) + p0 + i) * Hh + tile * HC;
      const float scal = (float)(p0 + i + 1);
#pragma unroll
      for (int k = 0; k < 3; ++k) {
        float4 v = *(const float4*)(xr + hs * 4 + k * 16);
        float vv[4] = {v.x, v.y, v.z, v.w};
#pragma unroll
        for (int c = 0; c < 4; ++c) {
          const int h = hs * 4 + k * 16 + c;
          sGT[h * 64 + (((i >> 3) ^ (h & 7)) << 3) + (i & 7)] = f2bf(vv[c] * scal);
        }
      }
    }
    __syncthreads();

    // ---- MFMA compute ----
    f32x4 accO[3] = {};
    {
      const int rj = w * 16 + lq;  // j-row (A for C1/C2), also d-row (B for D)
      bf16x8 aC1[2], aC2[2], bD[2];
#pragma unroll
      for (int ks = 0; ks < 2; ++ks) {
        const int blk = ((ks * 4 + quad) ^ (rj & 7)) << 3;
        aC1[ks] = *(const bf16x8*)(sSc + rj * 64 + blk);
        aC2[ks] = *(const bf16x8*)(sE + rj * 64 + blk);
        bD[ks] = *(const bf16x8*)(sFT + rj * 64 + blk);
      }
#pragma unroll
      for (int ht = 0; ht < 3; ++ht) {
        const int rh = ht * 16 + lq;
#pragma unroll
        for (int ks = 0; ks < 2; ++ks) {
          const int blk = ((ks * 4 + quad) ^ (rh & 7)) << 3;
          bf16x8 g = *(const bf16x8*)(sGT + rh * 64 + blk);
          bf16x8 st = *(const bf16x8*)(sST + rh * 64 + blk);
          accO[ht] = __builtin_amdgcn_mfma_f32_16x16x32_bf16(aC1[ks], g, accO[ht], 0, 0, 0);
          accO[ht] = __builtin_amdgcn_mfma_f32_16x16x32_bf16(aC2[ks], st, accO[ht], 0, 0, 0);
          accS[ht] = __builtin_amdgcn_mfma_f32_16x16x32_bf16(g, bD[ks], accS[ht], 0, 0, 0);
        }
      }
    }

    // ---- epilogue: out = x + acc/(j+1) ----
#pragma unroll
    for (int ht = 0; ht < 3; ++ht) {
#pragma unroll
      for (int r = 0; r < 4; ++r) {
        const int j = w * 16 + quad * 4 + r;
        const int gj = p0 + j;
        const size_t off = ((size_t)(b * Ll) + gj) * Hh + tile * HC + ht * 16 + lq;
        out[off] = bx[off] + accO[ht][r] * (1.0f / (float)(gj + 1));
      }
    }
    __syncthreads();

    // ---- dump updated state (bf16) for next chunk's C2 operand ----
#pragma unroll
    for (int ht = 0; ht < 3; ++ht) {
#pragma unroll
      for (int r = 0; r < 4; ++r) {
        const int h = ht * 16 + quad * 4 + r;  // row m of D-result
        const int d = w * 16 + lq;             // col n of D-result
        sST[h * 64 + (((d >> 3) ^ (h & 7)) << 3) + (d & 7)] = f2bf(accS[ht][r]);
      }
    }
  }
}

extern "C" void kernel_launch(void* const* d_in, const int* in_sizes, int n_in,
                              void* d_out, int out_size, void* d_ws, size_t ws_size,
                              hipStream_t stream) {
  (void)in_sizes; (void)n_in; (void)out_size; (void)ws_size;
  const float* bx = (const float*)d_in[0];
  const int* x = (const int*)d_in[1];
  const float* ae = (const float*)d_in[2];
  const float* w = (const float*)d_in[3];
  float* out = (float*)d_out;
  short* Eg = (short*)d_ws;                       // 512*4096 bf16 = 4 MB
  short* FTg = Eg + (size_t)512 * 4096;           // 4 MB
  short* scTg = FTg + (size_t)512 * 4096;         // 4 MB

  prep_kernel<<<Bb * NCH, 256, 0, stream>>>(x, ae, w, Eg, FTg, scTg);
  dim3 grid(NT, Bb);
  scan_kernel<<<grid, 256, 0, stream>>>(bx, Eg, FTg, scTg, out);
}

// Round 3
// 254.477 us; speedup vs baseline: 2.3813x; 1.2336x over previous
//
#include <hip/hip_runtime.h>

#define Bb 16
#define Ll 2048
#define Hh 768
#define Dd 64
#define Cc 64
#define HC 48
#define NT (Hh / HC)   // 16 h-tiles
#define NCH (Ll / Cc)  // 32 chunks

typedef __attribute__((ext_vector_type(8))) short bf16x8;
typedef __attribute__((ext_vector_type(4))) float f32x4;

__device__ __forceinline__ short f2bf(float f) {
  union { float f; unsigned u; } c;
  c.f = f;
  unsigned r = (c.u + 0x7FFFu + ((c.u >> 16) & 1u)) >> 16;
  return (short)r;
}
__device__ __forceinline__ unsigned pack2(float a, float b) {
  return (unsigned)(unsigned short)f2bf(a) | ((unsigned)(unsigned short)f2bf(b) << 16);
}

// CK-style barrier: waits LDS ops only; global prefetch loads stay in flight.
__device__ __forceinline__ void sync_lds() {
  asm volatile("s_waitcnt lgkmcnt(0)\n\ts_barrier" ::: "memory");
}

// ---------------- Prep: per (b,chunk) -> bf16 E[64][64], FT[64][64], scT[64][64] ----------------
__global__ __launch_bounds__(256) void prep_kernel(const int* __restrict__ x,
                                                   const float* __restrict__ ae,
                                                   const float* __restrict__ w,
                                                   short* __restrict__ Eg,
                                                   short* __restrict__ FTg,
                                                   short* __restrict__ scTg) {
  const int tid = threadIdx.x;
  const int wv = tid >> 6, lane = tid & 63, quad = lane >> 4, lq = lane & 15;
  const int b = blockIdx.x >> 5, ch = blockIdx.x & 31;
  const size_t gb = (size_t)blockIdx.x * 4096;
  __shared__ short sE[64 * 64];   // rows i, cols d (swizzled)
  __shared__ short sWT[64 * 64];  // rows e, cols d (swizzled) = w^T
  __shared__ short sF[64 * 64];   // rows i, cols e (swizzled)

  // gather E rows -> sE + Eg;  stage w^T
  {
    const int i = tid >> 2, seg = tid & 3;
    const int idx = x[b * Ll + ch * Cc + i];
    const float4* aer = (const float4*)(ae + (size_t)idx * Dd) + seg * 4;
    float4 ev[4];
#pragma unroll
    for (int q = 0; q < 4; ++q) ev[q] = aer[q];
    uint4 pA, pB;
    pA.x = pack2(ev[0].x, ev[0].y); pA.y = pack2(ev[0].z, ev[0].w);
    pA.z = pack2(ev[1].x, ev[1].y); pA.w = pack2(ev[1].z, ev[1].w);
    pB.x = pack2(ev[2].x, ev[2].y); pB.y = pack2(ev[2].z, ev[2].w);
    pB.z = pack2(ev[3].x, ev[3].y); pB.w = pack2(ev[3].z, ev[3].w);
    *(uint4*)&sE[i * 64 + (((2 * seg) ^ (i & 7)) << 3)] = pA;
    *(uint4*)&sE[i * 64 + (((2 * seg + 1) ^ (i & 7)) << 3)] = pB;
    *(uint4*)(Eg + gb + i * 64 + seg * 16) = pA;
    *(uint4*)(Eg + gb + i * 64 + seg * 16 + 8) = pB;
    const float4* wr = (const float4*)w;
#pragma unroll
    for (int q = 0; q < 4; ++q) {
      const int fl = q * 256 + tid;
      const int d = fl >> 4, es = (fl & 15) * 4;
      const float4 v = wr[fl];
      const float vv[4] = {v.x, v.y, v.z, v.w};
#pragma unroll
      for (int c = 0; c < 4; ++c) {
        const int e = es + c;
        sWT[e * 64 + (((d >> 3) ^ (e & 7)) << 3) + (d & 7)] = f2bf(vv[c]);
      }
    }
  }
  __syncthreads();

  const int rm = wv * 16 + lq;
  bf16x8 aE[2], aW[2];
#pragma unroll
  for (int ks = 0; ks < 2; ++ks) {
    const int blk = ((ks * 4 + quad) ^ (rm & 7)) << 3;
    aE[ks] = *(const bf16x8*)&sE[rm * 64 + blk];
    aW[ks] = *(const bf16x8*)&sWT[rm * 64 + blk];
  }

  // F[i][e] = sum_d E[i][d] w[d][e]  -> sF ;  FT[e][i] -> FTg
#pragma unroll
  for (int nt = 0; nt < 4; ++nt) {
    const int rn = nt * 16 + lq;
    f32x4 accF = {}, accT = {};
#pragma unroll
    for (int ks = 0; ks < 2; ++ks) {
      const int blk = ((ks * 4 + quad) ^ (rn & 7)) << 3;
      const bf16x8 bW = *(const bf16x8*)&sWT[rn * 64 + blk];
      const bf16x8 bE = *(const bf16x8*)&sE[rn * 64 + blk];
      accF = __builtin_amdgcn_mfma_f32_16x16x32_bf16(aE[ks], bW, accF, 0, 0, 0);
      accT = __builtin_amdgcn_mfma_f32_16x16x32_bf16(aW[ks], bE, accT, 0, 0, 0);
    }
#pragma unroll
    for (int r = 0; r < 4; ++r) {
      const int i = wv * 16 + quad * 4 + r;   // m of accF
      const int e = nt * 16 + lq;
      sF[i * 64 + (((e >> 3) ^ (i & 7)) << 3) + (e & 7)] = f2bf(accF[r]);
      const int e2 = wv * 16 + quad * 4 + r;  // m of accT
      const int i2 = nt * 16 + lq;
      FTg[gb + e2 * 64 + i2] = f2bf(accT[r]);
    }
  }
  __syncthreads();

  // sc[j][i] = sum_e E[j][e] F[i][e], strict mask i<j -> scTg rows j
#pragma unroll
  for (int nt = 0; nt < 4; ++nt) {
    const int rn = nt * 16 + lq;
    f32x4 acc = {};
#pragma unroll
    for (int ks = 0; ks < 2; ++ks) {
      const int blk = ((ks * 4 + quad) ^ (rn & 7)) << 3;
      const bf16x8 bF = *(const bf16x8*)&sF[rn * 64 + blk];
      acc = __builtin_amdgcn_mfma_f32_16x16x32_bf16(aE[ks], bF, acc, 0, 0, 0);
    }
#pragma unroll
    for (int r = 0; r < 4; ++r) {
      const int j = wv * 16 + quad * 4 + r;
      const int i = nt * 16 + lq;
      scTg[gb + j * 64 + i] = f2bf(i < j ? acc[r] : 0.f);
    }
  }
}

// ---------------- Scan: pipelined MFMA chunked causal scan ----------------
__global__ __launch_bounds__(256) void scan_kernel(const float* __restrict__ bx,
                                                   const short* __restrict__ Eg,
                                                   const short* __restrict__ FTg,
                                                   const short* __restrict__ scTg,
                                                   float* __restrict__ out) {
  const int tile = blockIdx.x;
  const int b = blockIdx.y;
  const int tid = threadIdx.x;
  const int w = tid >> 6, lane = tid & 63, quad = lane >> 4, lq = lane & 15;

  __shared__ short sE[64 * 64];
  __shared__ short sSc[64 * 64];
  __shared__ short sFT[64 * 64];
  __shared__ short sGT[48 * 64];
  __shared__ short sST[48 * 64];

  f32x4 accS[3] = {};
  uint4 rE[2], rS[2], rF[2];
  float2 rG[6];
  float rB[12];

  const int ip = tid & 31, hg = tid >> 5;

  auto load_chunk = [&](int ch) {
    const size_t tb = (size_t)(b * NCH + ch) * 4096;
    const uint4* gE = (const uint4*)(Eg + tb);
    const uint4* gS = (const uint4*)(scTg + tb);
    const uint4* gF = (const uint4*)(FTg + tb);
#pragma unroll
    for (int t2 = 0; t2 < 2; ++t2) {
      const int idx = t2 * 256 + tid;
      rE[t2] = gE[idx];
      rS[t2] = gS[idx];
      rF[t2] = gF[idx];
    }
    const int p0 = ch * Cc;
    const float* xr = bx + ((size_t)(b * Ll) + p0 + 2 * ip) * Hh + tile * HC + hg * 6;
#pragma unroll
    for (int k = 0; k < 3; ++k) {
      rG[k] = *(const float2*)(xr + 2 * k);
      rG[3 + k] = *(const float2*)(xr + Hh + 2 * k);
    }
    const float* br = bx + ((size_t)(b * Ll) + p0 + w * 16 + quad * 4) * Hh + tile * HC + lq;
#pragma unroll
    for (int ht = 0; ht < 3; ++ht)
#pragma unroll
      for (int r = 0; r < 4; ++r) rB[ht * 4 + r] = br[(size_t)r * Hh + ht * 16];
  };

  load_chunk(0);

  for (int ch = 0; ch < NCH; ++ch) {
    const int p0 = ch * Cc;
    sync_lds();  // barrier A: prev chunk's LDS reads done

    // tiles regs -> LDS (16B-block XOR swizzle)
#pragma unroll
    for (int t2 = 0; t2 < 2; ++t2) {
      const int idx = t2 * 256 + tid;
      const int r_ = idx >> 3, bl = idx & 7;
      const int dst = r_ * 64 + ((bl ^ (r_ & 7)) << 3);
      *(uint4*)&sE[dst] = rE[t2];
      *(uint4*)&sSc[dst] = rS[t2];
      *(uint4*)&sFT[dst] = rF[t2];
    }
    // G: paired-i dword writes, conflict-free
    {
      const float s0 = (float)(p0 + 2 * ip + 1), s1 = (float)(p0 + 2 * ip + 2);
#pragma unroll
      for (int k = 0; k < 3; ++k) {
#pragma unroll
        for (int c = 0; c < 2; ++c) {
          const int h = hg * 6 + 2 * k + c;
          const float g0 = (c ? rG[k].y : rG[k].x) * s0;
          const float g1 = (c ? rG[3 + k].y : rG[3 + k].x) * s1;
          const int sa = h * 64 + (((ip >> 2) ^ (h & 7)) << 3) + 2 * (ip & 3);
          *(unsigned*)&sGT[sa] = pack2(g0, g1);
        }
      }
    }
    // dump state S^T (accS holds S after chunks < ch; zero at ch=0)
#pragma unroll
    for (int ht = 0; ht < 3; ++ht)
#pragma unroll
      for (int r = 0; r < 4; ++r) {
        const int h = ht * 16 + quad * 4 + r;
        const int d = w * 16 + lq;
        sST[h * 64 + (((d >> 3) ^ (h & 7)) << 3) + (d & 7)] = f2bf(accS[ht][r]);
      }

    // keep this chunk's epilogue bx, then prefetch next chunk
    float myB[12];
#pragma unroll
    for (int q = 0; q < 12; ++q) myB[q] = rB[q];
    load_chunk(ch + 1 < NCH ? ch + 1 : NCH - 1);

    sync_lds();  // barrier B: LDS tiles visible

    // MFMA compute
    f32x4 accO[3] = {};
    {
      const int rj = w * 16 + lq;
      bf16x8 aC1[2], aC2[2], bD[2];
#pragma unroll
      for (int ks = 0; ks < 2; ++ks) {
        const int blk = ((ks * 4 + quad) ^ (rj & 7)) << 3;
        aC1[ks] = *(const bf16x8*)(sSc + rj * 64 + blk);
        aC2[ks] = *(const bf16x8*)(sE + rj * 64 + blk);
        bD[ks] = *(const bf16x8*)(sFT + rj * 64 + blk);
      }
#pragma unroll
      for (int ht = 0; ht < 3; ++ht) {
        const int rh = ht * 16 + lq;
#pragma unroll
        for (int ks = 0; ks < 2; ++ks) {
          const int blk = ((ks * 4 + quad) ^ (rh & 7)) << 3;
          bf16x8 g = *(const bf16x8*)(sGT + rh * 64 + blk);
          bf16x8 st = *(const bf16x8*)(sST + rh * 64 + blk);
          accO[ht] = __builtin_amdgcn_mfma_f32_16x16x32_bf16(aC1[ks], g, accO[ht], 0, 0, 0);
          accO[ht] = __builtin_amdgcn_mfma_f32_16x16x32_bf16(aC2[ks], st, accO[ht], 0, 0, 0);
          accS[ht] = __builtin_amdgcn_mfma_f32_16x16x32_bf16(g, bD[ks], accS[ht], 0, 0, 0);
        }
      }
    }

    // epilogue: out = bx + accO/(j+1)
#pragma unroll
    for (int ht = 0; ht < 3; ++ht) {
#pragma unroll
      for (int r = 0; r < 4; ++r) {
        const int gj = p0 + w * 16 + quad * 4 + r;
        const size_t off = ((size_t)(b * Ll) + gj) * Hh + tile * HC + ht * 16 + lq;
        out[off] = myB[ht * 4 + r] + accO[ht][r] * (1.0f / (float)(gj + 1));
      }
    }
  }
}

extern "C" void kernel_launch(void* const* d_in, const int* in_sizes, int n_in,
                              void* d_out, int out_size, void* d_ws, size_t ws_size,
                              hipStream_t stream) {
  (void)in_sizes; (void)n_in; (void)out_size; (void)ws_size;
  const float* bx = (const float*)d_in[0];
  const int* x = (const int*)d_in[1];
  const float* ae = (const float*)d_in[2];
  const float* w = (const float*)d_in[3];
  float* out = (float*)d_out;
  short* Eg = (short*)d_ws;                       // 512*4096 bf16 = 4 MB
  short* FTg = Eg + (size_t)512 * 4096;           // 4 MB
  short* scTg = FTg + (size_t)512 * 4096;         // 4 MB

  prep_kernel<<<Bb * NCH, 256, 0, stream>>>(x, ae, w, Eg, FTg, scTg);
  dim3 grid(NT, Bb);
  scan_kernel<<<grid, 256, 0, stream>>>(bx, Eg, FTg, scTg, out);
}